// Round 2
// baseline (10318.812 us; speedup 1.0000x reference)
//
#include <hip/hip_runtime.h>
#include <hip/hip_bf16.h>
#include <stdint.h>

#define T_STEPS 512
#define BATCH   256
#define DIN     85
#define HDIM    512
#define NOUT    33

#define GRP   16     // blocks per group
#define BBLK  16     // batch rows per group
#define HS    32     // H columns per block
#define LDA   1040   // bytes per padded row of h A-tile (520 elems, 16B-aligned, bank-safe)
#define LDX   208    // bytes per padded row of x A-tile (104 elems)

typedef __attribute__((ext_vector_type(8))) short s8v;   // 8 x bf16 (4 VGPRs)
typedef __attribute__((ext_vector_type(4))) float f4v;   // MFMA accumulator

__device__ __forceinline__ uint16_t f2bf(float f) {
    uint32_t x = __builtin_bit_cast(uint32_t, f);
    uint32_t r = (x + 0x7fffu + ((x >> 16) & 1u)) >> 16;
    return (uint16_t)r;
}
__device__ __forceinline__ float sigm(float v) {
    v = fminf(fmaxf(v, -30.f), 30.f);
    return 1.f / (1.f + __expf(-v));
}
__device__ __forceinline__ float tanh_f(float v) {
    v = fminf(fmaxf(v, -15.f), 15.f);
    float e = __expf(2.f * v);
    return (e - 1.f) / (e + 1.f);
}
// 8 consecutive floats -> 8 bf16 lanes (RNE)
__device__ __forceinline__ s8v cvt8(const float* p) {
    s8v v;
#pragma unroll
    for (int j = 0; j < 8; ++j) v[j] = (short)f2bf(p[j]);
    return v;
}

// Persistent recurrence kernel. 256 blocks = 16 groups x 16 members.
// Group owns 16 batch rows; member owns 32 H columns (x4 gates).
// Weights (Wh, Wx) live in registers as MFMA B-fragments for the whole kernel.
__global__ __launch_bounds__(256, 1) void lstm_rec(
    const float* __restrict__ x,
    const float* __restrict__ Wxi, const float* __restrict__ Wxf,
    const float* __restrict__ Wxo, const float* __restrict__ Wxc,
    const float* __restrict__ Whi, const float* __restrict__ bhi,
    const float* __restrict__ Whf, const float* __restrict__ bhf,
    const float* __restrict__ Who, const float* __restrict__ bho,
    const float* __restrict__ Whc, const float* __restrict__ bhc,
    uint16_t* __restrict__ hbuf,      // [T_STEPS+1][BATCH][HDIM] bf16 (internal scratch)
    unsigned int* __restrict__ flags) // [16][640]
{
    __shared__ __align__(16) uint8_t hA[16 * LDA];   // 16.6 KB
    __shared__ __align__(16) uint8_t xA[16 * LDX];   // 3.3 KB
    __shared__ float gbuf[4 * 16 * 33];              // 8.4 KB (stride 33: bank-safe)

    const int tid  = threadIdx.x;
    const int bid  = blockIdx.x;
    // XCD-locality swizzle (heuristic only; correctness is scope-based)
    const int xcd  = bid & 7;
    const int slot = bid >> 3;
    const int grp  = xcd * 2 + (slot >> 4);
    const int mem  = slot & 15;
    const int b0   = grp * BBLK;
    const int hs   = mem * HS;

    const int wave  = tid >> 6;       // = gate: 0=i 1=f 2=o 3=c
    const int lane  = tid & 63;
    const int col16 = lane & 15;
    const int quad  = lane >> 4;

    const float* Wh  = (wave == 0) ? Whi : (wave == 1) ? Whf : (wave == 2) ? Who : Whc;
    const float* Wxp = (wave == 0) ? Wxi : (wave == 1) ? Wxf : (wave == 2) ? Wxo : Wxc;

    // ---- B-fragments (weights) into registers, once (fp32 -> bf16 RNE) ----
    s8v bh[2][16];
#pragma unroll
    for (int nt = 0; nt < 2; ++nt) {
        const float* rowp = Wh + (size_t)(hs + nt * 16 + col16) * HDIM;
#pragma unroll
        for (int kt = 0; kt < 16; ++kt)
            bh[nt][kt] = cvt8(rowp + kt * 32 + quad * 8);
    }
    s8v bx[2][3];
#pragma unroll
    for (int nt = 0; nt < 2; ++nt) {
        const float* rowp = Wxp + (size_t)(hs + nt * 16 + col16) * DIN;
#pragma unroll
        for (int kt = 0; kt < 3; ++kt) {
            s8v v;
#pragma unroll
            for (int j = 0; j < 8; ++j) {
                int k = kt * 32 + quad * 8 + j;
                v[j] = (k < DIN) ? (short)f2bf(rowp[k]) : (short)0;
            }
            bx[nt][kt] = v;
        }
    }

    // ---- pointwise thread mapping: (b, hcol) and (b+8, hcol) ----
    const int pw_col = tid & 31;
    const int pw_b   = tid >> 5;   // 0..7
    const float bi = bhi[hs + pw_col];
    const float bf = bhf[hs + pw_col];
    const float bo = bho[hs + pw_col];
    const float bc = bhc[hs + pw_col];
    float C0 = 0.f, C1 = 0.f;

    // ---- x prefetch (fp32 registers) ----
    float xreg[6];
    auto load_x = [&](int t) {
#pragma unroll
        for (int j = 0; j < 6; ++j) {
            int v = tid + j * 256;          // 0..1535
            int row = v / 96, k = v % 96;
            xreg[j] = (k < DIN) ? x[(size_t)(t * BATCH + b0 + row) * DIN + k] : 0.f;
        }
    };
    auto store_x = [&]() {
#pragma unroll
        for (int j = 0; j < 6; ++j) {
            int v = tid + j * 256;
            int row = v / 96, k = v % 96;
            *(uint16_t*)(xA + row * LDX + k * 2) = f2bf(xreg[j]);
        }
    };

    // init: h(0)=0 in LDS, stage x(0)
    load_x(0);
    for (int j = tid; j < 16 * LDA / 16; j += 256) {
        s8v z;
#pragma unroll
        for (int q = 0; q < 8; ++q) z[q] = 0;
        ((s8v*)hA)[j] = z;
    }
    store_x();
    __syncthreads();

    unsigned int* flg = flags + grp * 640;

    for (int t = 0; t < T_STEPS; ++t) {
        // ---- GEMM: pre[16 x 32-outs] for this wave's gate ----
        f4v acc0 = {0.f, 0.f, 0.f, 0.f}, acc1 = {0.f, 0.f, 0.f, 0.f};
#pragma unroll
        for (int kt = 0; kt < 16; ++kt) {
            s8v a = *(const s8v*)(hA + col16 * LDA + kt * 64 + quad * 16);
            acc0 = __builtin_amdgcn_mfma_f32_16x16x32_bf16(a, bh[0][kt], acc0, 0, 0, 0);
            acc1 = __builtin_amdgcn_mfma_f32_16x16x32_bf16(a, bh[1][kt], acc1, 0, 0, 0);
        }
#pragma unroll
        for (int kt = 0; kt < 3; ++kt) {
            s8v a = *(const s8v*)(xA + col16 * LDX + kt * 64 + quad * 16);
            acc0 = __builtin_amdgcn_mfma_f32_16x16x32_bf16(a, bx[0][kt], acc0, 0, 0, 0);
            acc1 = __builtin_amdgcn_mfma_f32_16x16x32_bf16(a, bx[1][kt], acc1, 0, 0, 0);
        }
        // C/D layout: col = lane&15, row = quad*4 + r
#pragma unroll
        for (int r = 0; r < 4; ++r) {
            int b = quad * 4 + r;
            gbuf[(wave * 16 + b) * 33 + col16]      = acc0[r];
            gbuf[(wave * 16 + b) * 33 + 16 + col16] = acc1[r];
        }
        __syncthreads();

        // ---- pointwise: 2 cells per thread ----
        float pi0 = gbuf[(0 * 16 + pw_b) * 33 + pw_col] + bi;
        float pf0 = gbuf[(1 * 16 + pw_b) * 33 + pw_col] + bf;
        float po0 = gbuf[(2 * 16 + pw_b) * 33 + pw_col] + bo;
        float pc0 = gbuf[(3 * 16 + pw_b) * 33 + pw_col] + bc;
        float pi1 = gbuf[(0 * 16 + pw_b + 8) * 33 + pw_col] + bi;
        float pf1 = gbuf[(1 * 16 + pw_b + 8) * 33 + pw_col] + bf;
        float po1 = gbuf[(2 * 16 + pw_b + 8) * 33 + pw_col] + bo;
        float pc1 = gbuf[(3 * 16 + pw_b + 8) * 33 + pw_col] + bc;

        float I0 = sigm(pi0), F0 = sigm(pf0), O0 = sigm(po0), G0 = tanh_f(pc0);
        float I1 = sigm(pi1), F1 = sigm(pf1), O1 = sigm(po1), G1 = tanh_f(pc1);
        C0 = F0 * C0 + I0 * G0;
        C1 = F1 * C1 + I1 * G1;
        float h0 = O0 * tanh_f(C0);
        float h1 = O1 * tanh_f(C1);

        uint16_t* hdst = hbuf + (size_t)(t + 1) * BATCH * HDIM;
        hdst[(size_t)(b0 + pw_b) * HDIM + hs + pw_col]     = f2bf(h0);
        hdst[(size_t)(b0 + pw_b + 8) * HDIM + hs + pw_col] = f2bf(h1);

        __builtin_amdgcn_fence(__ATOMIC_RELEASE, "agent");
        __syncthreads();

        if (t == T_STEPS - 1) break;

        load_x(t + 1);  // loads stay in flight during the poll below

        if (tid == 0) {
            __hip_atomic_fetch_add(&flg[t], 1u, __ATOMIC_RELAXED, __HIP_MEMORY_SCOPE_AGENT);
            int guard = 0;
            while (__hip_atomic_load(&flg[t], __ATOMIC_RELAXED, __HIP_MEMORY_SCOPE_AGENT) < GRP) {
                __builtin_amdgcn_s_sleep(1);
                if (++guard > 2000000) break;   // safety valve: wrong answer beats a hang
            }
        }
        __syncthreads();
        __builtin_amdgcn_fence(__ATOMIC_ACQUIRE, "agent");

        // refill full h(t+1) tile (16 rows x 512) into LDS
        const uint16_t* src = hbuf + (size_t)(t + 1) * BATCH * HDIM + (size_t)b0 * HDIM;
#pragma unroll
        for (int j = 0; j < 4; ++j) {
            int v = tid + j * 256;     // 0..1023 16-byte chunks
            int row = v >> 6, c8 = v & 63;
            s8v val = *(const s8v*)(src + row * HDIM + c8 * 8);
            *(s8v*)(hA + row * LDA + c8 * 16) = val;
        }
        store_x();
        __syncthreads();
    }
}

// Readout: out[t,b,:] = h[t+1] @ Wro^T + bro.  MFMA, N padded 33->48. fp32 out.
__global__ __launch_bounds__(256, 1) void lstm_out(
    const uint16_t* __restrict__ hbuf,
    const float* __restrict__ Wro, const float* __restrict__ bro,
    float* __restrict__ out)
{
    __shared__ __align__(16) uint8_t hT[64 * LDA];   // 66.6 KB

    const int tid   = threadIdx.x;
    const int bid   = blockIdx.x;
    const int wave  = tid >> 6;
    const int lane  = tid & 63;
    const int col16 = lane & 15;
    const int quad  = lane >> 4;

    s8v bw[3][16];
    float bias[3];
#pragma unroll
    for (int nt = 0; nt < 3; ++nt) {
        int o = nt * 16 + col16;
        bias[nt] = (o < NOUT) ? bro[o] : 0.f;
#pragma unroll
        for (int kt = 0; kt < 16; ++kt) {
            if (o < NOUT) {
                bw[nt][kt] = cvt8(Wro + (size_t)o * HDIM + kt * 32 + quad * 8);
            } else {
                s8v z;
#pragma unroll
                for (int q = 0; q < 8; ++q) z[q] = 0;
                bw[nt][kt] = z;
            }
        }
    }

    const uint16_t* hsrc = hbuf + (size_t)BATCH * HDIM;  // skip t=0 slot

    for (int sub = 0; sub < 8; ++sub) {
        size_t row0 = (size_t)bid * 512 + (size_t)sub * 64;
        // stage 64 rows x 512 bf16
#pragma unroll
        for (int j = 0; j < 16; ++j) {
            int v = tid + j * 256;     // 0..4095 chunks
            int row = v >> 6, c8 = v & 63;
            s8v val = *(const s8v*)(hsrc + (row0 + row) * HDIM + c8 * 8);
            *(s8v*)(hT + row * LDA + c8 * 16) = val;
        }
        __syncthreads();

        f4v acc[3];
#pragma unroll
        for (int nt = 0; nt < 3; ++nt) acc[nt] = (f4v){0.f, 0.f, 0.f, 0.f};
#pragma unroll
        for (int kt = 0; kt < 16; ++kt) {
            s8v a = *(const s8v*)(hT + (wave * 16 + col16) * LDA + kt * 64 + quad * 16);
#pragma unroll
            for (int nt = 0; nt < 3; ++nt)
                acc[nt] = __builtin_amdgcn_mfma_f32_16x16x32_bf16(a, bw[nt][kt], acc[nt], 0, 0, 0);
        }
#pragma unroll
        for (int nt = 0; nt < 3; ++nt) {
            int o = nt * 16 + col16;
            if (o < NOUT) {
#pragma unroll
                for (int r = 0; r < 4; ++r) {
                    size_t rg = row0 + (size_t)wave * 16 + quad * 4 + r;
                    out[rg * NOUT + o] = acc[nt][r] + bias[nt];
                }
            }
        }
        __syncthreads();
    }
}

extern "C" void kernel_launch(void* const* d_in, const int* in_sizes, int n_in,
                              void* d_out, int out_size, void* d_ws, size_t ws_size,
                              hipStream_t stream)
{
    const float* x   = (const float*)d_in[0];
    const float* Wxi = (const float*)d_in[1];
    const float* Wxf = (const float*)d_in[2];
    const float* Wxo = (const float*)d_in[3];
    const float* Wxc = (const float*)d_in[4];
    const float* Whi = (const float*)d_in[5];
    const float* bhi = (const float*)d_in[6];
    const float* Whf = (const float*)d_in[7];
    const float* bhf = (const float*)d_in[8];
    const float* Who = (const float*)d_in[9];
    const float* bho = (const float*)d_in[10];
    const float* Whc = (const float*)d_in[11];
    const float* bhc = (const float*)d_in[12];
    const float* Wro = (const float*)d_in[13];
    const float* bro = (const float*)d_in[14];
    float* out = (float*)d_out;

    uint8_t* ws = (uint8_t*)d_ws;
    unsigned int* flags = (unsigned int*)ws;                 // 16*640*4 = 40960 B
    uint16_t* hbuf = (uint16_t*)(ws + 65536);                // (T+1)*B*H*2 = 134.5 MB

    hipMemsetAsync(flags, 0, 16 * 640 * sizeof(unsigned int), stream);
    lstm_rec<<<256, 256, 0, stream>>>(x, Wxi, Wxf, Wxo, Wxc,
                                      Whi, bhi, Whf, bhf, Who, bho, Whc, bhc,
                                      hbuf, flags);
    lstm_out<<<256, 256, 0, stream>>>(hbuf, Wro, bro, out);
}

// Round 3
// 2957.488 us; speedup vs baseline: 3.4890x; 3.4890x over previous
//
#include <hip/hip_runtime.h>
#include <hip/hip_bf16.h>
#include <stdint.h>

#define T_STEPS 512
#define BATCH   256
#define DIN     85
#define HDIM    512
#define NOUT    33

#define GRP   16     // blocks per group
#define BBLK  16     // batch rows per group
#define HS    32     // H columns per block
#define LDA   1040   // bytes per padded row of h A-tile (520 elems, 16B-aligned)
#define LDX   208    // bytes per padded row of x A-tile (104 elems)

typedef __attribute__((ext_vector_type(8))) short s8v;   // 8 x bf16 (4 VGPRs)
typedef __attribute__((ext_vector_type(4))) float f4v;   // MFMA accumulator

__device__ __forceinline__ uint16_t f2bf(float f) {
    uint32_t x = __builtin_bit_cast(uint32_t, f);
    uint32_t r = (x + 0x7fffu + ((x >> 16) & 1u)) >> 16;
    return (uint16_t)r;
}
__device__ __forceinline__ float sigm(float v) {
    v = fminf(fmaxf(v, -30.f), 30.f);
    return 1.f / (1.f + __expf(-v));
}
__device__ __forceinline__ float tanh_f(float v) {
    v = fminf(fmaxf(v, -15.f), 15.f);
    float e = __expf(2.f * v);
    return (e - 1.f) / (e + 1.f);
}
__device__ __forceinline__ s8v cvt8(const float* p) {
    s8v v;
#pragma unroll
    for (int j = 0; j < 8; ++j) v[j] = (short)f2bf(p[j]);
    return v;
}

// Persistent recurrence kernel. 256 blocks = 16 groups x 16 members.
// Group owns 16 batch rows; member owns 32 H columns (x4 gates, one per wave).
// Weights live in registers as MFMA B-fragments for the whole kernel.
// Cross-block h exchange: relaxed agent-scope atomics (sc0/sc1 write-through
// loads/stores at the device coherence point) — NO acquire/release fences,
// hence no buffer_wbl2/buffer_inv L2 maintenance (the 20us/step killer in R2).
// Ordering: __syncthreads drains each wave's vmcnt(0); an sc1 store that has
// retired vmcnt is visible device-wide, so flag-store-after-barrier is a
// sufficient release, and readers' sc1 loads after flag observation are a
// sufficient acquire.
__global__ __launch_bounds__(256, 1) void lstm_rec(
    const float* __restrict__ x,
    const float* __restrict__ Wxi, const float* __restrict__ Wxf,
    const float* __restrict__ Wxo, const float* __restrict__ Wxc,
    const float* __restrict__ Whi, const float* __restrict__ bhi,
    const float* __restrict__ Whf, const float* __restrict__ bhf,
    const float* __restrict__ Who, const float* __restrict__ bho,
    const float* __restrict__ Whc, const float* __restrict__ bhc,
    uint16_t* __restrict__ hbuf,      // [T_STEPS+1][BATCH][HDIM] bf16 (scratch)
    unsigned int* __restrict__ flags) // [16 groups][T_STEPS][16 members]
{
    __shared__ __align__(16) uint8_t hA[16 * LDA];   // 16.6 KB
    __shared__ __align__(16) uint8_t xA[16 * LDX];   // 3.3 KB
    __shared__ float gbuf[4 * 16 * 33];              // 8.4 KB (stride 33)

    const int tid  = threadIdx.x;
    const int bid  = blockIdx.x;
    const int xcd  = bid & 7;
    const int slot = bid >> 3;
    const int grp  = xcd * 2 + (slot >> 4);
    const int mem  = slot & 15;
    const int b0   = grp * BBLK;
    const int hs   = mem * HS;

    const int wave  = tid >> 6;       // gate: 0=i 1=f 2=o 3=c
    const int lane  = tid & 63;
    const int col16 = lane & 15;
    const int quad  = lane >> 4;

    const float* Wh  = (wave == 0) ? Whi : (wave == 1) ? Whf : (wave == 2) ? Who : Whc;
    const float* Wxp = (wave == 0) ? Wxi : (wave == 1) ? Wxf : (wave == 2) ? Wxo : Wxc;

    // ---- B-fragments (weights) into registers, once (fp32 -> bf16 RNE) ----
    s8v bh[2][16];
#pragma unroll
    for (int nt = 0; nt < 2; ++nt) {
        const float* rowp = Wh + (size_t)(hs + nt * 16 + col16) * HDIM;
#pragma unroll
        for (int kt = 0; kt < 16; ++kt)
            bh[nt][kt] = cvt8(rowp + kt * 32 + quad * 8);
    }
    s8v bx[2][3];
#pragma unroll
    for (int nt = 0; nt < 2; ++nt) {
        const float* rowp = Wxp + (size_t)(hs + nt * 16 + col16) * DIN;
#pragma unroll
        for (int kt = 0; kt < 3; ++kt) {
            s8v v;
#pragma unroll
            for (int j = 0; j < 8; ++j) {
                int k = kt * 32 + quad * 8 + j;
                v[j] = (k < DIN) ? (short)f2bf(rowp[k]) : (short)0;
            }
            bx[nt][kt] = v;
        }
    }

    // ---- pointwise mapping: thread -> (row r, cols c0,c0+1) of 16x32 slice ----
    const int r    = tid >> 4;           // 0..15 batch row within group
    const int c0   = (tid & 15) * 2;     // even col within 32-col slice
    const float bi0 = bhi[hs + c0], bi1 = bhi[hs + c0 + 1];
    const float bf0 = bhf[hs + c0], bf1 = bhf[hs + c0 + 1];
    const float bo0 = bho[hs + c0], bo1 = bho[hs + c0 + 1];
    const float bc0 = bhc[hs + c0], bc1 = bhc[hs + c0 + 1];
    float C0 = 0.f, C1 = 0.f;

    uint32_t* hbuf32 = (uint32_t*)hbuf;
    // this thread's packed h store slot (u32 = 2 bf16), per step offset added later
    const size_t hslot = ((size_t)(b0 + r) * HDIM + hs + c0) >> 1;

    // ---- x prefetch (fp32 registers) ----
    float xreg[6];
    auto load_x = [&](int t) {
#pragma unroll
        for (int j = 0; j < 6; ++j) {
            int v = tid + j * 256;          // 0..1535
            int row = v / 96, k = v % 96;
            xreg[j] = (k < DIN) ? x[(size_t)(t * BATCH + b0 + row) * DIN + k] : 0.f;
        }
    };
    auto store_x = [&]() {
#pragma unroll
        for (int j = 0; j < 6; ++j) {
            int v = tid + j * 256;
            int row = v / 96, k = v % 96;
            *(uint16_t*)(xA + row * LDX + k * 2) = f2bf(xreg[j]);
        }
    };

    // init: h(0)=0 in LDS, stage x(0)
    load_x(0);
    for (int j = tid; j < 16 * LDA / 16; j += 256) {
        s8v z;
#pragma unroll
        for (int q = 0; q < 8; ++q) z[q] = 0;
        ((s8v*)hA)[j] = z;
    }
    store_x();
    __syncthreads();

    unsigned int* flg = flags + (size_t)grp * T_STEPS * GRP;

    for (int t = 0; t < T_STEPS; ++t) {
        // ---- GEMM: pre-activations for this wave's gate, 16 rows x 32 cols ----
        f4v acc0 = {0.f, 0.f, 0.f, 0.f}, acc1 = {0.f, 0.f, 0.f, 0.f};
#pragma unroll
        for (int kt = 0; kt < 16; ++kt) {
            s8v a = *(const s8v*)(hA + col16 * LDA + kt * 64 + quad * 16);
            acc0 = __builtin_amdgcn_mfma_f32_16x16x32_bf16(a, bh[0][kt], acc0, 0, 0, 0);
            acc1 = __builtin_amdgcn_mfma_f32_16x16x32_bf16(a, bh[1][kt], acc1, 0, 0, 0);
        }
#pragma unroll
        for (int kt = 0; kt < 3; ++kt) {
            s8v a = *(const s8v*)(xA + col16 * LDX + kt * 64 + quad * 16);
            acc0 = __builtin_amdgcn_mfma_f32_16x16x32_bf16(a, bx[0][kt], acc0, 0, 0, 0);
            acc1 = __builtin_amdgcn_mfma_f32_16x16x32_bf16(a, bx[1][kt], acc1, 0, 0, 0);
        }
        // C/D layout: col = lane&15, row = quad*4 + reg
#pragma unroll
        for (int rr = 0; rr < 4; ++rr) {
            int b = quad * 4 + rr;
            gbuf[(wave * 16 + b) * 33 + col16]      = acc0[rr];
            gbuf[(wave * 16 + b) * 33 + 16 + col16] = acc1[rr];
        }
        __syncthreads();

        // ---- pointwise: one row, two adjacent cols per thread ----
        float pi0 = gbuf[(0 * 16 + r) * 33 + c0] + bi0;
        float pi1 = gbuf[(0 * 16 + r) * 33 + c0 + 1] + bi1;
        float pf0 = gbuf[(1 * 16 + r) * 33 + c0] + bf0;
        float pf1 = gbuf[(1 * 16 + r) * 33 + c0 + 1] + bf1;
        float po0 = gbuf[(2 * 16 + r) * 33 + c0] + bo0;
        float po1 = gbuf[(2 * 16 + r) * 33 + c0 + 1] + bo1;
        float pc0 = gbuf[(3 * 16 + r) * 33 + c0] + bc0;
        float pc1 = gbuf[(3 * 16 + r) * 33 + c0 + 1] + bc1;

        float I0 = sigm(pi0), F0 = sigm(pf0), O0 = sigm(po0), G0 = tanh_f(pc0);
        float I1 = sigm(pi1), F1 = sigm(pf1), O1 = sigm(po1), G1 = tanh_f(pc1);
        C0 = F0 * C0 + I0 * G0;
        C1 = F1 * C1 + I1 * G1;
        float h0 = O0 * tanh_f(C0);
        float h1 = O1 * tanh_f(C1);

        // packed write-through store to coherence point (no fence needed)
        uint32_t packed = (uint32_t)f2bf(h0) | ((uint32_t)f2bf(h1) << 16);
        __hip_atomic_store(&hbuf32[(size_t)(t + 1) * (BATCH * HDIM / 2) + hslot],
                           packed, __ATOMIC_RELAXED, __HIP_MEMORY_SCOPE_AGENT);

        // barrier drains each wave's vmcnt(0) -> all h stores visible agent-wide
        __syncthreads();

        if (t == T_STEPS - 1) break;

        load_x(t + 1);  // input loads fly during the poll below

        if (tid == 0)   // per-member flag: plain atomic store, no contended RMW
            __hip_atomic_store(&flg[t * GRP + mem], 1u,
                               __ATOMIC_RELAXED, __HIP_MEMORY_SCOPE_AGENT);
        if (wave == 0) {
            // lanes 0..15 poll all 16 member slots in one coalesced round-trip
            int guard = 0;
            for (;;) {
                unsigned int v = 1u;
                if (lane < GRP)
                    v = __hip_atomic_load(&flg[t * GRP + lane],
                                          __ATOMIC_RELAXED, __HIP_MEMORY_SCOPE_AGENT);
                unsigned long long miss = __ballot(v == 0);
                if (!miss) break;
                __builtin_amdgcn_s_sleep(1);
                if (++guard > 2000000) break;   // safety valve: never hang
            }
        }
        __syncthreads();

        // refill h(t+1) tile (16 rows x 512 = 4096 u32) via coherent loads.
        // Must bypass L2: a 128B line spans two members' column slices, so the
        // local L2 copy can be half-stale. sc1 atomic loads read the fresh line.
        const uint32_t* src = hbuf32 + (size_t)(t + 1) * (BATCH * HDIM / 2)
                                     + (size_t)b0 * (HDIM / 2);
#pragma unroll
        for (int j = 0; j < 16; ++j) {
            uint32_t val = __hip_atomic_load(&src[(size_t)j * (HDIM / 2) + tid],
                                             __ATOMIC_RELAXED, __HIP_MEMORY_SCOPE_AGENT);
            *(uint32_t*)(hA + j * LDA + tid * 4) = val;
        }
        store_x();
        __syncthreads();
    }
}

// Readout: out[t,b,:] = h[t+1] @ Wro^T + bro.  MFMA, N padded 33->48. fp32 out.
__global__ __launch_bounds__(256, 1) void lstm_out(
    const uint16_t* __restrict__ hbuf,
    const float* __restrict__ Wro, const float* __restrict__ bro,
    float* __restrict__ out)
{
    __shared__ __align__(16) uint8_t hT[64 * LDA];   // 66.6 KB

    const int tid   = threadIdx.x;
    const int bid   = blockIdx.x;
    const int wave  = tid >> 6;
    const int lane  = tid & 63;
    const int col16 = lane & 15;
    const int quad  = lane >> 4;

    s8v bw[3][16];
    float bias[3];
#pragma unroll
    for (int nt = 0; nt < 3; ++nt) {
        int o = nt * 16 + col16;
        bias[nt] = (o < NOUT) ? bro[o] : 0.f;
#pragma unroll
        for (int kt = 0; kt < 16; ++kt) {
            if (o < NOUT) {
                bw[nt][kt] = cvt8(Wro + (size_t)o * HDIM + kt * 32 + quad * 8);
            } else {
                s8v z;
#pragma unroll
                for (int q = 0; q < 8; ++q) z[q] = 0;
                bw[nt][kt] = z;
            }
        }
    }

    const uint16_t* hsrc = hbuf + (size_t)BATCH * HDIM;  // skip t=0 slot

    for (int sub = 0; sub < 8; ++sub) {
        size_t row0 = (size_t)bid * 512 + (size_t)sub * 64;
#pragma unroll
        for (int j = 0; j < 16; ++j) {
            int v = tid + j * 256;
            int row = v >> 6, c8 = v & 63;
            s8v val = *(const s8v*)(hsrc + (row0 + row) * HDIM + c8 * 8);
            *(s8v*)(hT + row * LDA + c8 * 16) = val;
        }
        __syncthreads();

        f4v acc[3];
#pragma unroll
        for (int nt = 0; nt < 3; ++nt) acc[nt] = (f4v){0.f, 0.f, 0.f, 0.f};
#pragma unroll
        for (int kt = 0; kt < 16; ++kt) {
            s8v a = *(const s8v*)(hT + (wave * 16 + col16) * LDA + kt * 64 + quad * 16);
#pragma unroll
            for (int nt = 0; nt < 3; ++nt)
                acc[nt] = __builtin_amdgcn_mfma_f32_16x16x32_bf16(a, bw[nt][kt], acc[nt], 0, 0, 0);
        }
#pragma unroll
        for (int nt = 0; nt < 3; ++nt) {
            int o = nt * 16 + col16;
            if (o < NOUT) {
#pragma unroll
                for (int rr = 0; rr < 4; ++rr) {
                    size_t rg = row0 + (size_t)wave * 16 + quad * 4 + rr;
                    out[rg * NOUT + o] = acc[nt][rr] + bias[nt];
                }
            }
        }
        __syncthreads();
    }
}

extern "C" void kernel_launch(void* const* d_in, const int* in_sizes, int n_in,
                              void* d_out, int out_size, void* d_ws, size_t ws_size,
                              hipStream_t stream)
{
    const float* x   = (const float*)d_in[0];
    const float* Wxi = (const float*)d_in[1];
    const float* Wxf = (const float*)d_in[2];
    const float* Wxo = (const float*)d_in[3];
    const float* Wxc = (const float*)d_in[4];
    const float* Whi = (const float*)d_in[5];
    const float* bhi = (const float*)d_in[6];
    const float* Whf = (const float*)d_in[7];
    const float* bhf = (const float*)d_in[8];
    const float* Who = (const float*)d_in[9];
    const float* bho = (const float*)d_in[10];
    const float* Whc = (const float*)d_in[11];
    const float* bhc = (const float*)d_in[12];
    const float* Wro = (const float*)d_in[13];
    const float* bro = (const float*)d_in[14];
    float* out = (float*)d_out;

    uint8_t* ws = (uint8_t*)d_ws;
    unsigned int* flags = (unsigned int*)ws;                 // 16*512*16*4 = 512 KB
    uint16_t* hbuf = (uint16_t*)(ws + (1 << 20));            // (T+1)*B*H*2 = 134.5 MB

    hipMemsetAsync(flags, 0, (size_t)16 * T_STEPS * GRP * sizeof(unsigned int), stream);
    lstm_rec<<<256, 256, 0, stream>>>(x, Wxi, Wxf, Wxo, Wxc,
                                      Whi, bhi, Whf, bhf, Who, bho, Whc, bhc,
                                      hbuf, flags);
    lstm_out<<<256, 256, 0, stream>>>(hbuf, Wro, bro, out);
}

// Round 4
// 2494.398 us; speedup vs baseline: 4.1368x; 1.1857x over previous
//
#include <hip/hip_runtime.h>
#include <hip/hip_bf16.h>
#include <stdint.h>

#define T_STEPS 512
#define BATCH   256
#define DIN     85
#define HDIM    512
#define NOUT    33

#define GRP   16     // blocks per group
#define BBLK  16     // batch rows per group
#define HS    32     // H columns per block
#define LDA   1040   // bytes per padded row of h A-tile (520 elems, 16B-aligned)
#define LDX   208    // bytes per padded row of x A-tile (104 elems)

// bf16 NaN|NaN pair — unreachable as packed h output (|h|<1, finite),
// used as the "not yet written" sentinel so the data is its own flag.
#define SENT  0x7FC07FC0u

typedef __attribute__((ext_vector_type(8))) short s8v;   // 8 x bf16 (4 VGPRs)
typedef __attribute__((ext_vector_type(4))) float f4v;   // MFMA accumulator

__device__ __forceinline__ uint16_t f2bf(float f) {
    uint32_t x = __builtin_bit_cast(uint32_t, f);
    uint32_t r = (x + 0x7fffu + ((x >> 16) & 1u)) >> 16;
    return (uint16_t)r;
}
__device__ __forceinline__ float sigm(float v) {
    v = fminf(fmaxf(v, -30.f), 30.f);
    return 1.f / (1.f + __expf(-v));
}
__device__ __forceinline__ float tanh_f(float v) {
    v = fminf(fmaxf(v, -15.f), 15.f);
    float e = __expf(2.f * v);
    return (e - 1.f) / (e + 1.f);
}
__device__ __forceinline__ s8v cvt8(const float* p) {
    s8v v;
#pragma unroll
    for (int j = 0; j < 8; ++j) v[j] = (short)f2bf(p[j]);
    return v;
}

// Fill hbuf with the sentinel before the recurrence (never rely on harness
// poison patterns). 513 slots x 64K u32 = 33.6M u32.
__global__ __launch_bounds__(256) void lstm_init(uint32_t* __restrict__ hbuf)
{
    typedef __attribute__((ext_vector_type(4))) unsigned int u4v;
    const size_t n4 = (size_t)(T_STEPS + 1) * BATCH * HDIM / 2 / 4;
    u4v s; s[0] = SENT; s[1] = SENT; s[2] = SENT; s[3] = SENT;
    u4v* p = (u4v*)hbuf;
    for (size_t i = (size_t)blockIdx.x * 256 + threadIdx.x; i < n4;
         i += (size_t)gridDim.x * 256)
        p[i] = s;
}

// Persistent recurrence kernel. 256 blocks = 16 groups x 16 members.
// Group owns 16 batch rows; member owns 32 H columns (x4 gates, one per wave).
// Weights live in registers as MFMA B-fragments for the whole kernel.
// Cross-block h exchange: sentinel protocol — producers fire-and-forget
// relaxed agent-scope stores of packed h (sc1 write-through, no fence, no
// vmcnt drain); consumers poll the data itself (sc1 loads) until every slot
// differs from SENT. One store-propagation + one observation RT per step,
// no flag line contention, 2 barriers/step.
__global__ __launch_bounds__(256, 1) void lstm_rec(
    const float* __restrict__ x,
    const float* __restrict__ Wxi, const float* __restrict__ Wxf,
    const float* __restrict__ Wxo, const float* __restrict__ Wxc,
    const float* __restrict__ Whi, const float* __restrict__ bhi,
    const float* __restrict__ Whf, const float* __restrict__ bhf,
    const float* __restrict__ Who, const float* __restrict__ bho,
    const float* __restrict__ Whc, const float* __restrict__ bhc,
    uint16_t* __restrict__ hbuf)      // [T_STEPS+1][BATCH][HDIM] bf16 (scratch)
{
    __shared__ __align__(16) uint8_t hA[16 * LDA];   // 16.6 KB
    __shared__ __align__(16) uint8_t xA[16 * LDX];   // 3.3 KB
    __shared__ float gbuf[4 * 16 * 33];              // 8.4 KB (stride 33)

    const int tid  = threadIdx.x;
    const int bid  = blockIdx.x;
    const int xcd  = bid & 7;
    const int slot = bid >> 3;
    const int grp  = xcd * 2 + (slot >> 4);
    const int mem  = slot & 15;
    const int b0   = grp * BBLK;
    const int hs   = mem * HS;

    const int wave  = tid >> 6;       // gate: 0=i 1=f 2=o 3=c
    const int lane  = tid & 63;
    const int col16 = lane & 15;
    const int quad  = lane >> 4;

    const float* Wh  = (wave == 0) ? Whi : (wave == 1) ? Whf : (wave == 2) ? Who : Whc;
    const float* Wxp = (wave == 0) ? Wxi : (wave == 1) ? Wxf : (wave == 2) ? Wxo : Wxc;

    // ---- B-fragments (weights) into registers, once (fp32 -> bf16 RNE) ----
    s8v bh[2][16];
#pragma unroll
    for (int nt = 0; nt < 2; ++nt) {
        const float* rowp = Wh + (size_t)(hs + nt * 16 + col16) * HDIM;
#pragma unroll
        for (int kt = 0; kt < 16; ++kt)
            bh[nt][kt] = cvt8(rowp + kt * 32 + quad * 8);
    }
    s8v bx[2][3];
#pragma unroll
    for (int nt = 0; nt < 2; ++nt) {
        const float* rowp = Wxp + (size_t)(hs + nt * 16 + col16) * DIN;
#pragma unroll
        for (int kt = 0; kt < 3; ++kt) {
            s8v v;
#pragma unroll
            for (int j = 0; j < 8; ++j) {
                int k = kt * 32 + quad * 8 + j;
                v[j] = (k < DIN) ? (short)f2bf(rowp[k]) : (short)0;
            }
            bx[nt][kt] = v;
        }
    }

    // ---- pointwise mapping: thread -> (row r, cols c0,c0+1) of 16x32 slice ----
    const int r    = tid >> 4;           // 0..15 batch row within group
    const int c0   = (tid & 15) * 2;     // even col within 32-col slice
    const float bi0 = bhi[hs + c0], bi1 = bhi[hs + c0 + 1];
    const float bf0 = bhf[hs + c0], bf1 = bhf[hs + c0 + 1];
    const float bo0 = bho[hs + c0], bo1 = bho[hs + c0 + 1];
    const float bc0 = bhc[hs + c0], bc1 = bhc[hs + c0 + 1];
    float C0 = 0.f, C1 = 0.f;

    uint32_t* hbuf32 = (uint32_t*)hbuf;
    const size_t hslot = ((size_t)(b0 + r) * HDIM + hs + c0) >> 1;

    // ---- x prefetch (fp32 registers) ----
    float xreg[6];
    auto load_x = [&](int t) {
#pragma unroll
        for (int j = 0; j < 6; ++j) {
            int v = tid + j * 256;          // 0..1535
            int row = v / 96, k = v % 96;
            xreg[j] = (k < DIN) ? x[(size_t)(t * BATCH + b0 + row) * DIN + k] : 0.f;
        }
    };
    auto store_x = [&]() {
#pragma unroll
        for (int j = 0; j < 6; ++j) {
            int v = tid + j * 256;
            int row = v / 96, k = v % 96;
            *(uint16_t*)(xA + row * LDX + k * 2) = f2bf(xreg[j]);
        }
    };

    // init: h(0)=0 in LDS, stage x(0)
    load_x(0);
    for (int j = tid; j < 16 * LDA / 16; j += 256) {
        s8v z;
#pragma unroll
        for (int q = 0; q < 8; ++q) z[q] = 0;
        ((s8v*)hA)[j] = z;
    }
    store_x();
    __syncthreads();

    for (int t = 0; t < T_STEPS; ++t) {
        // ---- GEMM: pre-activations for this wave's gate, 16 rows x 32 cols ----
        f4v acc0 = {0.f, 0.f, 0.f, 0.f}, acc1 = {0.f, 0.f, 0.f, 0.f};
#pragma unroll
        for (int kt = 0; kt < 16; ++kt) {
            s8v a = *(const s8v*)(hA + col16 * LDA + kt * 64 + quad * 16);
            acc0 = __builtin_amdgcn_mfma_f32_16x16x32_bf16(a, bh[0][kt], acc0, 0, 0, 0);
            acc1 = __builtin_amdgcn_mfma_f32_16x16x32_bf16(a, bh[1][kt], acc1, 0, 0, 0);
        }
#pragma unroll
        for (int kt = 0; kt < 3; ++kt) {
            s8v a = *(const s8v*)(xA + col16 * LDX + kt * 64 + quad * 16);
            acc0 = __builtin_amdgcn_mfma_f32_16x16x32_bf16(a, bx[0][kt], acc0, 0, 0, 0);
            acc1 = __builtin_amdgcn_mfma_f32_16x16x32_bf16(a, bx[1][kt], acc1, 0, 0, 0);
        }
        // C/D layout: col = lane&15, row = quad*4 + reg
#pragma unroll
        for (int rr = 0; rr < 4; ++rr) {
            int b = quad * 4 + rr;
            gbuf[(wave * 16 + b) * 33 + col16]      = acc0[rr];
            gbuf[(wave * 16 + b) * 33 + 16 + col16] = acc1[rr];
        }

        // x(t+1) loads fly during pointwise + poll
        if (t < T_STEPS - 1) load_x(t + 1);

        __syncthreads();   // gbuf complete; hA reads of this step done

        // ---- pointwise: one row, two adjacent cols per thread ----
        float pi0 = gbuf[(0 * 16 + r) * 33 + c0] + bi0;
        float pi1 = gbuf[(0 * 16 + r) * 33 + c0 + 1] + bi1;
        float pf0 = gbuf[(1 * 16 + r) * 33 + c0] + bf0;
        float pf1 = gbuf[(1 * 16 + r) * 33 + c0 + 1] + bf1;
        float po0 = gbuf[(2 * 16 + r) * 33 + c0] + bo0;
        float po1 = gbuf[(2 * 16 + r) * 33 + c0 + 1] + bo1;
        float pc0 = gbuf[(3 * 16 + r) * 33 + c0] + bc0;
        float pc1 = gbuf[(3 * 16 + r) * 33 + c0 + 1] + bc1;

        float I0 = sigm(pi0), F0 = sigm(pf0), O0 = sigm(po0), G0 = tanh_f(pc0);
        float I1 = sigm(pi1), F1 = sigm(pf1), O1 = sigm(po1), G1 = tanh_f(pc1);
        C0 = F0 * C0 + I0 * G0;
        C1 = F1 * C1 + I1 * G1;
        float h0 = O0 * tanh_f(C0);
        float h1 = O1 * tanh_f(C1);

        // fire-and-forget write-through store; no drain, no flag
        uint32_t packed = (uint32_t)f2bf(h0) | ((uint32_t)f2bf(h1) << 16);
        __hip_atomic_store(&hbuf32[(size_t)(t + 1) * (BATCH * HDIM / 2) + hslot],
                           packed, __ATOMIC_RELAXED, __HIP_MEMORY_SCOPE_AGENT);

        if (t == T_STEPS - 1) break;

        // ---- refill h(t+1): poll the data itself (sentinel protocol) ----
        const uint32_t* src = hbuf32 + (size_t)(t + 1) * (BATCH * HDIM / 2)
                                     + (size_t)b0 * (HDIM / 2);
        uint32_t vals[16];
#pragma unroll
        for (int j = 0; j < 16; ++j)
            vals[j] = __hip_atomic_load(&src[(size_t)j * (HDIM / 2) + tid],
                                        __ATOMIC_RELAXED, __HIP_MEMORY_SCOPE_AGENT);
        int guard = 0;
        for (;;) {
            uint32_t miss = 0;
#pragma unroll
            for (int j = 0; j < 16; ++j) {
                if (vals[j] == SENT)
                    vals[j] = __hip_atomic_load(&src[(size_t)j * (HDIM / 2) + tid],
                                                __ATOMIC_RELAXED, __HIP_MEMORY_SCOPE_AGENT);
                miss |= (uint32_t)(vals[j] == SENT);
            }
            if (!miss) break;
            if (++guard > 20000) break;   // safety valve: never hang
        }
#pragma unroll
        for (int j = 0; j < 16; ++j)
            *(uint32_t*)(hA + j * LDA + tid * 4) = vals[j];

        store_x();
        __syncthreads();   // hA/xA staged for next step
    }
}

// Readout: out[t,b,:] = h[t+1] @ Wro^T + bro.  MFMA, N padded 33->48. fp32 out.
__global__ __launch_bounds__(256, 1) void lstm_out(
    const uint16_t* __restrict__ hbuf,
    const float* __restrict__ Wro, const float* __restrict__ bro,
    float* __restrict__ out)
{
    __shared__ __align__(16) uint8_t hT[64 * LDA];   // 66.6 KB

    const int tid   = threadIdx.x;
    const int bid   = blockIdx.x;
    const int wave  = tid >> 6;
    const int lane  = tid & 63;
    const int col16 = lane & 15;
    const int quad  = lane >> 4;

    s8v bw[3][16];
    float bias[3];
#pragma unroll
    for (int nt = 0; nt < 3; ++nt) {
        int o = nt * 16 + col16;
        bias[nt] = (o < NOUT) ? bro[o] : 0.f;
#pragma unroll
        for (int kt = 0; kt < 16; ++kt) {
            if (o < NOUT) {
                bw[nt][kt] = cvt8(Wro + (size_t)o * HDIM + kt * 32 + quad * 8);
            } else {
                s8v z;
#pragma unroll
                for (int q = 0; q < 8; ++q) z[q] = 0;
                bw[nt][kt] = z;
            }
        }
    }

    const uint16_t* hsrc = hbuf + (size_t)BATCH * HDIM;  // skip t=0 slot

    for (int sub = 0; sub < 8; ++sub) {
        size_t row0 = (size_t)bid * 512 + (size_t)sub * 64;
#pragma unroll
        for (int j = 0; j < 16; ++j) {
            int v = tid + j * 256;
            int row = v >> 6, c8 = v & 63;
            s8v val = *(const s8v*)(hsrc + (row0 + row) * HDIM + c8 * 8);
            *(s8v*)(hT + row * LDA + c8 * 16) = val;
        }
        __syncthreads();

        f4v acc[3];
#pragma unroll
        for (int nt = 0; nt < 3; ++nt) acc[nt] = (f4v){0.f, 0.f, 0.f, 0.f};
#pragma unroll
        for (int kt = 0; kt < 16; ++kt) {
            s8v a = *(const s8v*)(hT + (wave * 16 + col16) * LDA + kt * 64 + quad * 16);
#pragma unroll
            for (int nt = 0; nt < 3; ++nt)
                acc[nt] = __builtin_amdgcn_mfma_f32_16x16x32_bf16(a, bw[nt][kt], acc[nt], 0, 0, 0);
        }
#pragma unroll
        for (int nt = 0; nt < 3; ++nt) {
            int o = nt * 16 + col16;
            if (o < NOUT) {
#pragma unroll
                for (int rr = 0; rr < 4; ++rr) {
                    size_t rg = row0 + (size_t)wave * 16 + quad * 4 + rr;
                    out[rg * NOUT + o] = acc[nt][rr] + bias[nt];
                }
            }
        }
        __syncthreads();
    }
}

extern "C" void kernel_launch(void* const* d_in, const int* in_sizes, int n_in,
                              void* d_out, int out_size, void* d_ws, size_t ws_size,
                              hipStream_t stream)
{
    const float* x   = (const float*)d_in[0];
    const float* Wxi = (const float*)d_in[1];
    const float* Wxf = (const float*)d_in[2];
    const float* Wxo = (const float*)d_in[3];
    const float* Wxc = (const float*)d_in[4];
    const float* Whi = (const float*)d_in[5];
    const float* bhi = (const float*)d_in[6];
    const float* Whf = (const float*)d_in[7];
    const float* bhf = (const float*)d_in[8];
    const float* Who = (const float*)d_in[9];
    const float* bho = (const float*)d_in[10];
    const float* Whc = (const float*)d_in[11];
    const float* bhc = (const float*)d_in[12];
    const float* Wro = (const float*)d_in[13];
    const float* bro = (const float*)d_in[14];
    float* out = (float*)d_out;

    uint16_t* hbuf = (uint16_t*)d_ws;   // (T+1)*B*H*2 = 134.5 MB

    lstm_init<<<2048, 256, 0, stream>>>((uint32_t*)hbuf);
    lstm_rec<<<256, 256, 0, stream>>>(x, Wxi, Wxf, Wxo, Wxc,
                                      Whi, bhi, Whf, bhf, Who, bho, Whc, bhc,
                                      hbuf);
    lstm_out<<<256, 256, 0, stream>>>(hbuf, Wro, bro, out);
}